// Round 4
// baseline (852.145 us; speedup 1.0000x reference)
//
#include <hip/hip_runtime.h>

#define B_ 512
#define T_ 48
#define D_ 128
#define F_ 16
#define H_ 512
// K = D_*F_ = 2048, gates = 4*H_ = 2048, M = T_*B_ = 24576

typedef float f32x4 __attribute__((ext_vector_type(4)));
typedef short s16x8 __attribute__((ext_vector_type(8)));
typedef unsigned short u16x8 __attribute__((ext_vector_type(8)));
typedef unsigned short u16x4 __attribute__((ext_vector_type(4)));
typedef unsigned long long u64;

__device__ __forceinline__ unsigned short f2bf(float x) {
  unsigned u = __float_as_uint(x);
  u += 0x7fffu + ((u >> 16) & 1u);   // round-to-nearest-even
  return (unsigned short)(u >> 16);
}
__device__ __forceinline__ float bf2f(unsigned short h) {
  return __uint_as_float(((unsigned)h) << 16);
}
// fast sigmoid/tanh via v_exp_f32 (exp2) + v_rcp_f32 (~1ulp; adds ~1e-6 rel err)
__device__ __forceinline__ float fsig(float x) {
  float e = __builtin_amdgcn_exp2f(-1.442695041f * x);
  return __builtin_amdgcn_rcpf(1.f + e);
}
__device__ __forceinline__ float ftanh(float x) {
  float e = __builtin_amdgcn_exp2f(2.885390082f * x);
  return 1.f - 2.f * __builtin_amdgcn_rcpf(1.f + e);
}

// Relaxed system-scope (sc0 sc1) accesses: bypass L1/L2, coherent at L3.
__device__ __forceinline__ void st_sys_u64(u64* p, u64 v) {
  __hip_atomic_store(p, v, __ATOMIC_RELAXED, __HIP_MEMORY_SCOPE_SYSTEM);
}
__device__ __forceinline__ u64 ld_sys_u64(const u64* p) {
  return __hip_atomic_load((u64*)p, __ATOMIC_RELAXED, __HIP_MEMORY_SCOPE_SYSTEM);
}
__device__ __forceinline__ void st_sys_u16(unsigned short* p, unsigned short v) {
  __hip_atomic_store(p, v, __ATOMIC_RELAXED, __HIP_MEMORY_SCOPE_SYSTEM);
}
__device__ __forceinline__ void st_sys_u32(unsigned* p, unsigned v) {
  __hip_atomic_store(p, v, __ATOMIC_RELAXED, __HIP_MEMORY_SCOPE_SYSTEM);
}
__device__ __forceinline__ unsigned ld_sys_u32(const unsigned* p) {
  return __hip_atomic_load((unsigned*)p, __ATOMIC_RELAXED, __HIP_MEMORY_SCOPE_SYSTEM);
}

#define AS1 __attribute__((address_space(1)))
#define AS3 __attribute__((address_space(3)))
__device__ __forceinline__ void g2lds16(const void* g, void* l) {
  __builtin_amdgcn_global_load_lds((const AS1 void*)g, (AS3 void*)l, 16, 0, 0);
}

// ---------------- K_prep: fp32 -> bf16 weight conversion ----------------
__global__ __launch_bounds__(256) void k_prep(const float* __restrict__ wih,
                                              const float* __restrict__ whh,
                                              unsigned short* __restrict__ wih_b,
                                              unsigned short* __restrict__ whh_b) {
  long i4 = ((long)blockIdx.x * 256 + threadIdx.x) * 4;
  if (i4 < 4194304) {
    float4 v = *(const float4*)(wih + i4);
    u16x4 o = {f2bf(v.x), f2bf(v.y), f2bf(v.z), f2bf(v.w)};
    *(u16x4*)(wih_b + i4) = o;
  } else {
    long j = i4 - 4194304;
    if (j < 1048576) {
      float4 v = *(const float4*)(whh + j);
      u16x4 o = {f2bf(v.x), f2bf(v.y), f2bf(v.z), f2bf(v.w)};
      *(u16x4*)(whh_b + j) = o;
    }
  }
}

// ---------------- K_ex: e_x = x_flat @ w_x + b, then softmax over D -----
__global__ __launch_bounds__(128) void k_ex(const float* __restrict__ in,
                                            const float* __restrict__ attn_w,
                                            const float* __restrict__ attn_b,
                                            float* __restrict__ a_out) {
  __shared__ float wx[768];
  __shared__ float red[128];
  const int b = blockIdx.x, d = threadIdx.x;
  for (int i = d; i < 768; i += 128) wx[i] = attn_w[1024 + i];
  __syncthreads();
  const float* base = in + (long)b * 98304 + (long)d * 16;
  float acc = 0.f;
  for (int t = 0; t < 48; ++t) {
    const float4* p = (const float4*)(base + (long)t * 2048);
    float4 v0 = p[0], v1 = p[1], v2 = p[2], v3 = p[3];
    acc += v0.x * wx[t]       + v0.y * wx[48 + t]  + v0.z * wx[96 + t]  + v0.w * wx[144 + t];
    acc += v1.x * wx[192 + t] + v1.y * wx[240 + t] + v1.z * wx[288 + t] + v1.w * wx[336 + t];
    acc += v2.x * wx[384 + t] + v2.y * wx[432 + t] + v2.z * wx[480 + t] + v2.w * wx[528 + t];
    acc += v3.x * wx[576 + t] + v3.y * wx[624 + t] + v3.z * wx[672 + t] + v3.w * wx[720 + t];
  }
  acc += attn_b[0];
  red[d] = acc;
  __syncthreads();
  for (int s = 64; s > 0; s >>= 1) {
    if (d < s) red[d] = fmaxf(red[d], red[d + s]);
    __syncthreads();
  }
  float mx = red[0];
  __syncthreads();
  float ex = expf(acc - mx);
  red[d] = ex;
  __syncthreads();
  for (int s = 64; s > 0; s >>= 1) {
    if (d < s) red[d] += red[d + s];
    __syncthreads();
  }
  a_out[b * 128 + d] = ex / red[0];
}

// ---------------- K_xhat: x_hat[t*512+b][d*16+f] = a[b,d]*x[b,t,d,f] (bf16)
__global__ __launch_bounds__(256) void k_xhat(const float* __restrict__ in,
                                              const float* __restrict__ a,
                                              unsigned short* __restrict__ xh) {
  const int mrow = blockIdx.x;            // t*512 + b
  const int t = mrow >> 9, b = mrow & 511;
  const int tid = threadIdx.x;
  const int k = tid * 8;
  const int d = k >> 4;
  const int f0 = k & 15;
  const float* src = in + (((long)(b * 48 + t) * 128 + d) * 16 + f0);
  float4 v0 = *(const float4*)src;
  float4 v1 = *(const float4*)(src + 4);
  float s = a[b * 128 + d];
  u16x8 o;
  o[0] = f2bf(v0.x * s); o[1] = f2bf(v0.y * s); o[2] = f2bf(v0.z * s); o[3] = f2bf(v0.w * s);
  o[4] = f2bf(v1.x * s); o[5] = f2bf(v1.y * s); o[6] = f2bf(v1.z * s); o[7] = f2bf(v1.w * s);
  *(u16x8*)(xh + (long)mrow * 2048 + k) = o;
}

// ---------------- K_gemm: 256x256 pipelined bf16 MFMA GEMM ----------------
// gates_x = x_hat(24576x2048) @ w_ih^T, bf16 in/out. BM=BN=256, BK=64,
// 512 thr = 8 waves (2M x 4N); per-wave C = 128x64.
// Round-4 change: B (w_ih, 8 MB, L2/L3-resident) is no longer LDS-staged;
// each wave loads its 8 B fragments per K-tile DIRECTLY to registers,
// double-buffered one tile ahead (issued at tile top, gated at tile end,
// ~2500+ cyc in flight > L3 latency). This halves LDS traffic per tile
// (192 -> 128 ds_read_b128/CU ~ 1536 cyc < MFMA 2483 cyc) so the LDS
// stream fits under the MFMA stream. A path unchanged from round 3
// (verified: conflicts == 0): full-BK 128B rows, LDS position p holds
// chunk p^(r&7), applied at the global source, XORed on read.
#define G_STAGEA(ktv, s)                                                        \
  do {                                                                          \
    const long ko_ = (long)(ktv) * 64 + (long)(s) * 262144;                     \
    char* la_ = (char*)SM + ((ktv) & 1) * 32768 + (s) * 16384 + ldsw;           \
    g2lds16(Ag + ko_, la_);                                                     \
    g2lds16(Ag + ko_ + 131072, la_ + 8192);                                     \
  } while (0)

#define G_LDA4(dst, bufel, ksv, mh)                                             \
  do {                                                                          \
    const unsigned short* ab_ =                                                 \
        SM + (bufel) + aBase + (mh) * 4096 + (psw ^ ((ksv) * 32));              \
    dst[0] = *(const s16x8*)(ab_);                                              \
    dst[1] = *(const s16x8*)(ab_ + 1024);                                       \
    dst[2] = *(const s16x8*)(ab_ + 2048);                                       \
    dst[3] = *(const s16x8*)(ab_ + 3072);                                       \
  } while (0)

#define G_LDBG(dst, ktv)                                                        \
  do {                                                                          \
    const unsigned short* bp_ = Bg + (long)(ktv) * 64;                          \
    _Pragma("unroll") for (int nt_ = 0; nt_ < 4; ++nt_)                         \
        _Pragma("unroll") for (int ks_ = 0; ks_ < 2; ++ks_)                     \
            dst[nt_][ks_] = *(const s16x8*)(bp_ + nt_ * 16 * 2048 + ks_ * 32);  \
  } while (0)

#define G_MMA2(mh, Af, BC, ksv)                                                 \
  do {                                                                          \
    __builtin_amdgcn_s_setprio(1);                                              \
    _Pragma("unroll") for (int mt_ = 0; mt_ < 4; ++mt_)                         \
        _Pragma("unroll") for (int nt_ = 0; nt_ < 4; ++nt_)                     \
            acc[(mh) * 4 + mt_][nt_] = __builtin_amdgcn_mfma_f32_16x16x32_bf16( \
                Af[mt_], BC[nt_][ksv], acc[(mh) * 4 + mt_][nt_], 0, 0, 0);      \
    __builtin_amdgcn_s_setprio(0);                                              \
  } while (0)

#define G_GATE(n) asm volatile("s_waitcnt vmcnt(" #n ")" ::: "memory")

// one K-tile: prefetch B(kt+1)->BN, stage A(kt+1), compute tile kt from BC
#define G_TILE(ktv, BC, BN)                                                     \
  do {                                                                          \
    const int bufel_ = ((ktv) & 1) * 16384;                                     \
    s16x8 a0[4], a1[4];                                                         \
    G_LDBG(BN, (ktv) + 1);                                                      \
    G_LDA4(a0, bufel_, 0, 0);                                                   \
    G_STAGEA((ktv) + 1, 0);                                                     \
    G_STAGEA((ktv) + 1, 1);                                                     \
    G_MMA2(0, a0, BC, 0);                                                       \
    G_LDA4(a1, bufel_, 0, 1);                                                   \
    G_MMA2(1, a1, BC, 0);                                                       \
    G_LDA4(a0, bufel_, 1, 0);                                                   \
    G_MMA2(0, a0, BC, 1);                                                       \
    G_LDA4(a1, bufel_, 1, 1);                                                   \
    G_MMA2(1, a1, BC, 1);                                                       \
    G_GATE(0);                                                                  \
    __builtin_amdgcn_s_barrier();                                               \
  } while (0)

__global__ __launch_bounds__(512, 2) void k_gemm(const unsigned short* __restrict__ A,
                                                 const unsigned short* __restrict__ Bw,
                                                 unsigned short* __restrict__ C) {
  __shared__ __align__(16) unsigned short SM[32768];  // A only: 2 x 32 KB dbuf
  const int tid = threadIdx.x;
  const int w = tid >> 6, lane = tid & 63;
  const int q = lane >> 4, l16 = lane & 15;
  const int wm = w >> 2, wn = w & 3;
  const int id = blockIdx.x;
  const int xcd = id & 7, j = id >> 3;                 // 768 = 8 XCD * 96, bijective
  const long m0 = ((long)xcd * 12 + (j >> 3)) * 256;   // 96 m-tiles
  const long n0 = (long)(j & 7) * 256;                 // 8 n-tiles, fastest

  // A staging: row = s*128 + i*64 + w*8 + (lane>>3), pos = lane&7; source
  // chunk pre-swizzled (csrc = pos ^ (row&7)) so linear LDS lands swizzled
  const int srow = w * 8 + (lane >> 3);
  const int csrc = (lane & 7) ^ (lane >> 3);
  const unsigned short* Ag = A + (m0 + srow) * 2048 + csrc * 8;
  const int ldsw = w * 1024;                           // wave-uniform LDS base

  // B direct-from-global fragment base: col = n0+wn*64+nt*16+l16, k = kt*64+ks*32+q*8
  const unsigned short* Bg = Bw + (n0 + wn * 64 + l16) * 2048 + q * 8;

  // A fragment read offsets; position = (ks*4+q) ^ (row&7), row&7 = l16&7
  const int psw = (q ^ (l16 & 7)) * 8;                 // ks1: psw ^ 32
  const int aBase = (wm * 128 + l16) * 64;             // + mh*4096 + mt*1024

  f32x4 acc[8][4];
  const f32x4 zz = {0.f, 0.f, 0.f, 0.f};
#pragma unroll
  for (int i = 0; i < 8; ++i)
#pragma unroll
    for (int j2 = 0; j2 < 4; ++j2) acc[i][j2] = zz;

  s16x8 bA[4][2], bB[4][2];
  // prologue: B frags tile0 -> bA, stage A tile0, drain, barrier
  G_LDBG(bA, 0);
  G_STAGEA(0, 0);
  G_STAGEA(0, 1);
  G_GATE(0);
  __builtin_amdgcn_s_barrier();

#pragma unroll 1
  for (int kt2 = 0; kt2 < 15; ++kt2) {
    const int kt = kt2 * 2;
    G_TILE(kt, bA, bB);
    G_TILE(kt + 1, bB, bA);
  }
  G_TILE(30, bA, bB);          // prefetches tile 31 into bB
  {  // kt = 31 (buf 1): drain tile, no prefetch/stage
    s16x8 a0[4], a1[4];
    G_LDA4(a0, 16384, 0, 0);
    G_MMA2(0, a0, bB, 0);
    G_LDA4(a1, 16384, 0, 1);
    G_MMA2(1, a1, bB, 0);
    G_LDA4(a0, 16384, 1, 0);
    G_MMA2(0, a0, bB, 1);
    G_LDA4(a1, 16384, 1, 1);
    G_MMA2(1, a1, bB, 1);
  }

  // epilogue: C[m][n], row = m0 + wm*128 + mh*64 + mt*16 + q*4 + r, col += l16
#pragma unroll
  for (int mh = 0; mh < 2; ++mh)
#pragma unroll
    for (int mt = 0; mt < 4; ++mt)
#pragma unroll
      for (int nt = 0; nt < 4; ++nt)
#pragma unroll
        for (int r = 0; r < 4; ++r) {
          long m = m0 + wm * 128 + mh * 64 + mt * 16 + q * 4 + r;
          long n = n0 + wn * 64 + nt * 16 + l16;
          C[m * 2048 + n] = f2bf(acc[mh * 4 + mt][nt][r]);
        }
}

// ---------------- K_rec: persistent LSTM scan (round-4 rewrite) ------------
// 256 blocks (bt 0..15, g 0..15), 4 waves. NEW decomposition: wave w owns
// k-chunks 4w..4w+3 (k = chunk*32..+32) for ALL 4 gate quadrants of this
// block's 32 gate cols. h fragments load straight from h_buf (L3) to
// registers per chunk (no LDS h-stage, no pre-MFMA block barrier; each wave
// waits only its own 4 producer flags). Own chunk g is served from an LDS
// mirror hs_own written at pointwise time (no own-flag L3 round trip).
// Cross-wave partial sums reduce through per-wave slabs laid out
// [(w*4+quad)*32+col][row pad36] so BOTH the MFMA-side f32x4 writes and the
// pointwise f32x4 reads (thread = col j, rows r0..r0+3) are conflict-free.
// w_hh fragments are loaded ONCE via volatile inline-asm global_load_dwordx4
// (cannot be rematerialized -> guaranteed VGPR-resident; round-3's
// VGPR_Count=120 < 128 proved the "+v" pin did NOT hold them, so the MFMA
// loop was re-reading w_hh from L2 every step).
__global__ __launch_bounds__(256, 1) void k_rec(const unsigned short* __restrict__ gx,
                                                const unsigned short* __restrict__ whh_b,
                                                const float* __restrict__ b_ih,
                                                const float* __restrict__ b_hh,
                                                unsigned short* __restrict__ h_buf,
                                                float* __restrict__ out,
                                                unsigned int* __restrict__ bar) {
  __shared__ __align__(16) float slab[16 * 32 * 36];      // 73728 B
  __shared__ __align__(16) unsigned short hs_own[32 * 40];// own h slice mirror
  const int tid = threadIdx.x;
  const int w = tid >> 6, lane = tid & 63;
  const int q = lane >> 4, l16 = lane & 15;
  const int bt = blockIdx.x & 15, g = blockIdx.x >> 4;
  const int b0 = bt * 32;
  const int pj = tid & 31;              // pointwise: col within g-block
  const int pr0 = (tid >> 5) * 4;       // pointwise: rows pr0..pr0+3
  unsigned int* slots = &bar[bt * 16];
  const int ownw = ((g >> 2) == w);     // this wave's range contains chunk g
  const int ownc = g & 3;

  // w_hh fragments -> registers, once, via volatile asm loads (not movable,
  // not rematerializable -> held in VGPRs for the whole kernel)
  s16x8 wreg[32];  // [(quad*2+nt)*4 + ci]
#pragma unroll
  for (int quad = 0; quad < 4; ++quad)
#pragma unroll
    for (int nt = 0; nt < 2; ++nt)
#pragma unroll
      for (int ci = 0; ci < 4; ++ci) {
        const unsigned short* wp =
            whh_b + (long)(quad * 512 + g * 32 + nt * 16 + l16) * 512 + (w * 4 + ci) * 32 + q * 8;
        asm volatile("global_load_dwordx4 %0, %1, off"
                     : "=v"(wreg[(quad * 2 + nt) * 4 + ci]) : "v"(wp) : "memory");
      }
  asm volatile("s_waitcnt vmcnt(0)" ::: "memory");
  __builtin_amdgcn_sched_barrier(0);

  float bias_[4];
#pragma unroll
  for (int qq = 0; qq < 4; ++qq) {
    int jj = qq * 512 + g * 32 + pj;
    bias_[qq] = b_ih[jj] + b_hh[jj];
  }
  float creg[4] = {0.f, 0.f, 0.f, 0.f};
  const f32x4 zz = {0.f, 0.f, 0.f, 0.f};

#define LD_CHUNK(slot, ci)                                                      \
  do {                                                                          \
    long o_ = hbase + (w * 4 + (ci)) * 8;                                       \
    L[slot][0] = ld_sys_u64(hb + o_);                                           \
    L[slot][1] = ld_sys_u64(hb + o_ + 1);                                       \
    L[slot][2] = ld_sys_u64(hb + o_ + 2048);                                    \
    L[slot][3] = ld_sys_u64(hb + o_ + 2049);                                    \
  } while (0)

  for (int t = 0; t < 48; ++t) {
    // gx prefetch (16 scalar u16; issued before any waiting)
    unsigned short gxr[4][4];
    const unsigned short* gp = gx + ((long)t * 512 + b0 + pr0) * 2048 + g * 32 + pj;
#pragma unroll
    for (int rr = 0; rr < 4; ++rr)
#pragma unroll
      for (int qq = 0; qq < 4; ++qq)
        gxr[qq][rr] = gp[rr * 2048 + qq * 512];

    if (t > 0) {
      // wait this wave's producer flags (lanes 0..3 poll; own chunk exempt)
      const int need = (lane < 4) && !(ownw && lane == ownc);
      const unsigned* fp = &slots[w * 4 + (lane & 3)];
      while (1) {
        unsigned v = need ? ld_sys_u32(fp) : 0xffffffffu;
        if (__all((int)(v >= (unsigned)t))) break;
      }
      // chunk pipeline: sys loads (L3) double-buffered, MFMA per chunk
      u64 L[2][4];
      const u64* hb = (const u64*)(h_buf + ((t - 1) & 1) * (512 * 512));
      const long hbase = (long)(b0 + l16) * 128 + q * 2;
      f32x4 acc[4][2][2];
#pragma unroll
      for (int a = 0; a < 4; ++a)
#pragma unroll
        for (int b = 0; b < 2; ++b)
#pragma unroll
          for (int c = 0; c < 2; ++c) acc[a][b][c] = zz;
      if (!(ownw && 0 == ownc)) LD_CHUNK(0, 0);
#pragma unroll
      for (int ci = 0; ci < 4; ++ci) {
        if (ci < 3 && !(ownw && (ci + 1) == ownc)) LD_CHUNK((ci + 1) & 1, ci + 1);
        s16x8 af0, af1;
        if (ownw && ci == ownc) {
          af0 = *(const s16x8*)&hs_own[l16 * 40 + q * 8];
          af1 = *(const s16x8*)&hs_own[(16 + l16) * 40 + q * 8];
        } else {
          union { u64 u[2]; s16x8 v; } c0, c1;
          c0.u[0] = L[ci & 1][0]; c0.u[1] = L[ci & 1][1];
          c1.u[0] = L[ci & 1][2]; c1.u[1] = L[ci & 1][3];
          af0 = c0.v; af1 = c1.v;
        }
#pragma unroll
        for (int quad = 0; quad < 4; ++quad)
#pragma unroll
          for (int nt = 0; nt < 2; ++nt) {
            acc[quad][nt][0] = __builtin_amdgcn_mfma_f32_16x16x32_bf16(
                af0, wreg[(quad * 2 + nt) * 4 + ci], acc[quad][nt][0], 0, 0, 0);
            acc[quad][nt][1] = __builtin_amdgcn_mfma_f32_16x16x32_bf16(
                af1, wreg[(quad * 2 + nt) * 4 + ci], acc[quad][nt][1], 0, 0, 0);
          }
      }
      // partials -> slab (f32x4 over rows, conflict-free)
#pragma unroll
      for (int quad = 0; quad < 4; ++quad)
#pragma unroll
        for (int nt = 0; nt < 2; ++nt)
#pragma unroll
          for (int mh = 0; mh < 2; ++mh)
            *(f32x4*)&slab[((w * 4 + quad) * 32 + nt * 16 + l16) * 36 + mh * 16 + q * 4] =
                acc[quad][nt][mh];
    }
    __syncthreads();

    // pointwise: thread owns (col g*32+pj, rows b0+pr0..+3)
    float hval[4];
    {
      f32x4 gs[4];
      if (t > 0) {
#pragma unroll
        for (int qq = 0; qq < 4; ++qq) {
          f32x4 s0 = *(const f32x4*)&slab[((0 * 4 + qq) * 32 + pj) * 36 + pr0];
          f32x4 s1 = *(const f32x4*)&slab[((1 * 4 + qq) * 32 + pj) * 36 + pr0];
          f32x4 s2 = *(const f32x4*)&slab[((2 * 4 + qq) * 32 + pj) * 36 + pr0];
          f32x4 s3 = *(const f32x4*)&slab[((3 * 4 + qq) * 32 + pj) * 36 + pr0];
          gs[qq] = (s0 + s1) + (s2 + s3);
        }
      } else {
#pragma unroll
        for (int qq = 0; qq < 4; ++qq) gs[qq] = zz;
      }
#pragma unroll
      for (int rr = 0; rr < 4; ++rr) {
        float g0 = gs[0][rr] + bias_[0] + bf2f(gxr[0][rr]);
        float g1 = gs[1][rr] + bias_[1] + bf2f(gxr[1][rr]);
        float g2 = gs[2][rr] + bias_[2] + bf2f(gxr[2][rr]);
        float g3 = gs[3][rr] + bias_[3] + bf2f(gxr[3][rr]);
        float is = fsig(g0);
        float fs = fsig(g1);
        float gt = ftanh(g2);
        float os = fsig(g3);
        creg[rr] = fs * creg[rr] + is * gt;
        hval[rr] = os * ftanh(creg[rr]);
      }
    }
    // publish h: LDS mirror (own chunk) + system-scope stores (L3, others)
#pragma unroll
    for (int rr = 0; rr < 4; ++rr) {
      unsigned short hb16 = f2bf(hval[rr]);
      hs_own[(pr0 + rr) * 40 + pj] = hb16;
      st_sys_u16(&h_buf[(t & 1) * (512 * 512) + (b0 + pr0 + rr) * 512 + g * 32 + pj], hb16);
    }
    __syncthreads();   // drains vmcnt(0): h stores at L3 before flag
    if (t < 47 && tid == 0)
      st_sys_u32(&slots[g], (unsigned)(t + 1));
    // out stores after the flag publish (drain overlaps next step's poll)
#pragma unroll
    for (int rr = 0; rr < 4; ++rr)
      __builtin_nontemporal_store(
          hval[rr], &out[(long)(b0 + pr0 + rr) * (T_ * H_) + (long)t * H_ + g * 32 + pj]);
  }
#undef LD_CHUNK
}

extern "C" void kernel_launch(void* const* d_in, const int* in_sizes, int n_in,
                              void* d_out, int out_size, void* d_ws, size_t ws_size,
                              hipStream_t stream) {
  const float* input  = (const float*)d_in[0];
  const float* attn_w = (const float*)d_in[1];
  const float* attn_b = (const float*)d_in[2];
  const float* w_ih   = (const float*)d_in[3];
  const float* w_hh   = (const float*)d_in[4];
  const float* b_ih   = (const float*)d_in[5];
  const float* b_hh   = (const float*)d_in[6];
  float* out = (float*)d_out;

  char* ws = (char*)d_ws;
  unsigned int* bar     = (unsigned int*)ws;                   // [0, 1024)
  float* a_ws           = (float*)(ws + 1024);                 // 512*128*4    = 262144
  unsigned short* h_buf = (unsigned short*)(ws + 263168);      // 2*512*512*2  = 1048576
  unsigned short* whh_b = (unsigned short*)(ws + 1311744);     // 2048*512*2   = 2097152
  unsigned short* wih_b = (unsigned short*)(ws + 3408896);     // 2048*2048*2  = 8388608
  unsigned short* x_hat = (unsigned short*)(ws + 11797504);    // 24576*2048*2 = 100663296
  unsigned short* gxws  = (unsigned short*)(ws + 112460800);   // 24576*2048*2 = 100663296

  (void)hipMemsetAsync(d_ws, 0, 1024, stream);
  hipLaunchKernelGGL(k_prep, dim3(5120), dim3(256), 0, stream, w_ih, w_hh, wih_b, whh_b);
  hipLaunchKernelGGL(k_ex, dim3(512), dim3(128), 0, stream, input, attn_w, attn_b, a_ws);
  hipLaunchKernelGGL(k_xhat, dim3(24576), dim3(256), 0, stream, input, a_ws, x_hat);
  hipLaunchKernelGGL(k_gemm, dim3(768), dim3(512), 0, stream, x_hat, wih_b, gxws);
  hipLaunchKernelGGL(k_rec, dim3(256), dim3(256), 0, stream, gxws, whh_b, b_ih, b_hh, h_buf, out, bar);
}

// Round 5
// 741.015 us; speedup vs baseline: 1.1500x; 1.1500x over previous
//
#include <hip/hip_runtime.h>

#define B_ 512
#define T_ 48
#define D_ 128
#define F_ 16
#define H_ 512
// K = D_*F_ = 2048, gates = 4*H_ = 2048, M = T_*B_ = 24576

typedef float f32x4 __attribute__((ext_vector_type(4)));
typedef short s16x8 __attribute__((ext_vector_type(8)));
typedef unsigned short u16x8 __attribute__((ext_vector_type(8)));
typedef unsigned short u16x4 __attribute__((ext_vector_type(4)));
typedef unsigned long long u64;

__device__ __forceinline__ unsigned short f2bf(float x) {
  unsigned u = __float_as_uint(x);
  u += 0x7fffu + ((u >> 16) & 1u);   // round-to-nearest-even
  return (unsigned short)(u >> 16);
}
__device__ __forceinline__ float bf2f(unsigned short h) {
  return __uint_as_float(((unsigned)h) << 16);
}
// fast sigmoid/tanh via v_exp_f32 (exp2) + v_rcp_f32 (~1ulp; adds ~1e-6 rel err)
__device__ __forceinline__ float fsig(float x) {
  float e = __builtin_amdgcn_exp2f(-1.442695041f * x);
  return __builtin_amdgcn_rcpf(1.f + e);
}
__device__ __forceinline__ float ftanh(float x) {
  float e = __builtin_amdgcn_exp2f(2.885390082f * x);
  return 1.f - 2.f * __builtin_amdgcn_rcpf(1.f + e);
}

// Relaxed system-scope (sc0 sc1) accesses: bypass L1/L2, coherent at L3.
__device__ __forceinline__ void st_sys_u64(u64* p, u64 v) {
  __hip_atomic_store(p, v, __ATOMIC_RELAXED, __HIP_MEMORY_SCOPE_SYSTEM);
}
__device__ __forceinline__ u64 ld_sys_u64(const u64* p) {
  return __hip_atomic_load((u64*)p, __ATOMIC_RELAXED, __HIP_MEMORY_SCOPE_SYSTEM);
}
__device__ __forceinline__ void st_sys_u16(unsigned short* p, unsigned short v) {
  __hip_atomic_store(p, v, __ATOMIC_RELAXED, __HIP_MEMORY_SCOPE_SYSTEM);
}
__device__ __forceinline__ void st_sys_u32(unsigned* p, unsigned v) {
  __hip_atomic_store(p, v, __ATOMIC_RELAXED, __HIP_MEMORY_SCOPE_SYSTEM);
}
__device__ __forceinline__ unsigned ld_sys_u32(const unsigned* p) {
  return __hip_atomic_load((unsigned*)p, __ATOMIC_RELAXED, __HIP_MEMORY_SCOPE_SYSTEM);
}

#define AS1 __attribute__((address_space(1)))
#define AS3 __attribute__((address_space(3)))
__device__ __forceinline__ void g2lds16(const void* g, void* l) {
  __builtin_amdgcn_global_load_lds((const AS1 void*)g, (AS3 void*)l, 16, 0, 0);
}

// ---------------- K_prep: fp32 -> bf16 weight conversion ----------------
__global__ __launch_bounds__(256) void k_prep(const float* __restrict__ wih,
                                              const float* __restrict__ whh,
                                              unsigned short* __restrict__ wih_b,
                                              unsigned short* __restrict__ whh_b) {
  long i4 = ((long)blockIdx.x * 256 + threadIdx.x) * 4;
  if (i4 < 4194304) {
    float4 v = *(const float4*)(wih + i4);
    u16x4 o = {f2bf(v.x), f2bf(v.y), f2bf(v.z), f2bf(v.w)};
    *(u16x4*)(wih_b + i4) = o;
  } else {
    long j = i4 - 4194304;
    if (j < 1048576) {
      float4 v = *(const float4*)(whh + j);
      u16x4 o = {f2bf(v.x), f2bf(v.y), f2bf(v.z), f2bf(v.w)};
      *(u16x4*)(whh_b + j) = o;
    }
  }
}

// ---------------- K_ex: e_x = x_flat @ w_x + b, then softmax over D -----
// Round-5: 256 threads (two t-halves per d) -> 2x waves/CU in the streaming
// phase; 512 blocks x 4 waves covers HBM latency (~22 KB/CU in flight).
__global__ __launch_bounds__(256) void k_ex(const float* __restrict__ in,
                                            const float* __restrict__ attn_w,
                                            const float* __restrict__ attn_b,
                                            float* __restrict__ a_out) {
  __shared__ float wx[768];
  __shared__ float red2[256];
  __shared__ float red[128];
  const int b = blockIdx.x, tid = threadIdx.x;
  const int d = tid & 127, half = tid >> 7;
  for (int i = tid; i < 768; i += 256) wx[i] = attn_w[1024 + i];
  __syncthreads();
  const float* base = in + (long)b * 98304 + (long)d * 16;
  float acc = 0.f;
  for (int t = half * 24; t < half * 24 + 24; ++t) {
    const float4* p = (const float4*)(base + (long)t * 2048);
    float4 v0 = p[0], v1 = p[1], v2 = p[2], v3 = p[3];
    acc += v0.x * wx[t]       + v0.y * wx[48 + t]  + v0.z * wx[96 + t]  + v0.w * wx[144 + t];
    acc += v1.x * wx[192 + t] + v1.y * wx[240 + t] + v1.z * wx[288 + t] + v1.w * wx[336 + t];
    acc += v2.x * wx[384 + t] + v2.y * wx[432 + t] + v2.z * wx[480 + t] + v2.w * wx[528 + t];
    acc += v3.x * wx[576 + t] + v3.y * wx[624 + t] + v3.z * wx[672 + t] + v3.w * wx[720 + t];
  }
  red2[tid] = acc;
  __syncthreads();
  float a2 = 0.f;
  if (tid < 128) {
    a2 = red2[tid] + red2[tid + 128] + attn_b[0];
    red[tid] = a2;
  }
  __syncthreads();
  for (int s = 64; s > 0; s >>= 1) {
    if (tid < s) red[tid] = fmaxf(red[tid], red[tid + s]);
    __syncthreads();
  }
  float mx = red[0];
  __syncthreads();
  float ex = 0.f;
  if (tid < 128) {
    ex = expf(a2 - mx);
    red[tid] = ex;
  }
  __syncthreads();
  for (int s = 64; s > 0; s >>= 1) {
    if (tid < s) red[tid] += red[tid + s];
    __syncthreads();
  }
  if (tid < 128) a_out[b * 128 + d] = ex / red[0];
}

// ---------------- K_xhat: x_hat[t*512+b][d*16+f] = a[b,d]*x[b,t,d,f] (bf16)
__global__ __launch_bounds__(256) void k_xhat(const float* __restrict__ in,
                                              const float* __restrict__ a,
                                              unsigned short* __restrict__ xh) {
  const int mrow = blockIdx.x;            // t*512 + b
  const int t = mrow >> 9, b = mrow & 511;
  const int tid = threadIdx.x;
  const int k = tid * 8;
  const int d = k >> 4;
  const int f0 = k & 15;
  const float* src = in + (((long)(b * 48 + t) * 128 + d) * 16 + f0);
  float4 v0 = *(const float4*)src;
  float4 v1 = *(const float4*)(src + 4);
  float s = a[b * 128 + d];
  u16x8 o;
  o[0] = f2bf(v0.x * s); o[1] = f2bf(v0.y * s); o[2] = f2bf(v0.z * s); o[3] = f2bf(v0.w * s);
  o[4] = f2bf(v1.x * s); o[5] = f2bf(v1.y * s); o[6] = f2bf(v1.z * s); o[7] = f2bf(v1.w * s);
  *(u16x8*)(xh + (long)mrow * 2048 + k) = o;
}

// ---------------- K_gemm: 256x256 pipelined bf16 MFMA GEMM ----------------
// ROUND-3 VERSION (reverted): round-4's B-direct-from-global regressed
// (per-lane B addresses stride 4 KB -> 64 cache lines per load inst ->
// VMEM-bound, MfmaUtil 28%). LDS-staged B via global_load_lds is coalesced.
// BM=BN=256, BK=64, 512 thr = 8 waves (2M x 4N); per-wave C = 128x64.
// LDS 128 KiB (1 block/CU): A [0,64K), B [64K,128K), double-buffered; row =
// full BK=64 (128 B, 8 chunks), swizzle: LDS position p holds chunk p^(r&7),
// applied at the GLOBAL source (global_load_lds writes linearly) and XORed
// on the read side -> conflict-free ds_read_b128 (verified: conflicts == 0).
// ONE barrier + ONE vmcnt(0) gate per K-tile; fragment loads are plain C++
// ds_reads issued phase-by-phase between MFMA clusters, so the compiler
// emits counted lgkmcnt waits and the LDS port drains during MFMA.

#define G_STAGE(ktv, s)                                                         \
  do {                                                                          \
    const long ko_ = (long)(ktv) * 64 + (long)(s) * 262144;                     \
    char* la_ = (char*)SM + ((ktv) & 1) * 32768 + (s) * 16384 + ldsw;           \
    g2lds16(Ag + ko_, la_);                                                     \
    g2lds16(Ag + ko_ + 131072, la_ + 8192);                                     \
    g2lds16(Bg + ko_, la_ + 65536);                                             \
    g2lds16(Bg + ko_ + 131072, la_ + 73728);                                    \
  } while (0)

#define G_LDA4(dst, bufel, ksv, mh)                                             \
  do {                                                                          \
    const unsigned short* ab_ =                                                 \
        SM + (bufel) + aBase + (mh) * 4096 + (psw ^ ((ksv) * 32));              \
    dst[0] = *(const s16x8*)(ab_);                                              \
    dst[1] = *(const s16x8*)(ab_ + 1024);                                       \
    dst[2] = *(const s16x8*)(ab_ + 2048);                                       \
    dst[3] = *(const s16x8*)(ab_ + 3072);                                       \
  } while (0)

#define G_LDB4(dst, bufel, ksv)                                                 \
  do {                                                                          \
    const unsigned short* bb_ = SM + (bufel) + bBase + (psw ^ ((ksv) * 32));    \
    dst[0] = *(const s16x8*)(bb_);                                              \
    dst[1] = *(const s16x8*)(bb_ + 1024);                                       \
    dst[2] = *(const s16x8*)(bb_ + 2048);                                       \
    dst[3] = *(const s16x8*)(bb_ + 3072);                                       \
  } while (0)

#define G_MMA2(mh, Af, Bf)                                                      \
  do {                                                                          \
    __builtin_amdgcn_s_setprio(1);                                              \
    _Pragma("unroll") for (int mt_ = 0; mt_ < 4; ++mt_)                         \
        _Pragma("unroll") for (int nt_ = 0; nt_ < 4; ++nt_)                     \
            acc[(mh) * 4 + mt_][nt_] = __builtin_amdgcn_mfma_f32_16x16x32_bf16( \
                Af[mt_], Bf[nt_], acc[(mh) * 4 + mt_][nt_], 0, 0, 0);           \
    __builtin_amdgcn_s_setprio(0);                                              \
  } while (0)

#define G_GATE(n) asm volatile("s_waitcnt vmcnt(" #n ")" ::: "memory")

__global__ __launch_bounds__(512, 2) void k_gemm(const unsigned short* __restrict__ A,
                                                 const unsigned short* __restrict__ Bw,
                                                 unsigned short* __restrict__ C) {
  __shared__ __align__(16) unsigned short SM[65536];  // A bytes [0,64K), B [64K,128K)
  const int tid = threadIdx.x;
  const int w = tid >> 6, lane = tid & 63;
  const int q = lane >> 4, l16 = lane & 15;
  const int wm = w >> 2, wn = w & 3;
  const int id = blockIdx.x;
  const int xcd = id & 7, j = id >> 3;                 // 768 = 8 XCD * 96, bijective
  const long m0 = ((long)xcd * 12 + (j >> 3)) * 256;   // 96 m-tiles
  const long n0 = (long)(j & 7) * 256;                 // 8 n-tiles, fastest

  // staging: thread covers (row = s*128 + i*64 + w*8 + (lane>>3), pos = lane&7);
  // source chunk pre-swizzled (csrc = pos ^ (row&7)) so linear LDS lands swizzled
  const int srow = w * 8 + (lane >> 3);
  const int csrc = (lane & 7) ^ (lane >> 3);
  const unsigned short* Ag = A + (m0 + srow) * 2048 + csrc * 8;
  const unsigned short* Bg = Bw + (n0 + srow) * 2048 + csrc * 8;
  const int ldsw = w * 1024;                           // wave-uniform LDS base

  // fragment read offsets (elements); position = (ks*4+q) ^ (row&7), row&7 = l16&7
  const int psw = (q ^ (l16 & 7)) * 8;                 // ks1: psw ^ 32
  const int aBase = (wm * 128 + l16) * 64;             // + mh*4096 + mt*1024
  const int bBase = 32768 + (wn * 64 + l16) * 64;      // + nt*1024

  f32x4 acc[8][4];
  const f32x4 zz = {0.f, 0.f, 0.f, 0.f};
#pragma unroll
  for (int i = 0; i < 8; ++i)
#pragma unroll
    for (int j2 = 0; j2 < 4; ++j2) acc[i][j2] = zz;

  // prologue: stage tile 0 fully, drain once (cold), barrier
  G_STAGE(0, 0);
  G_STAGE(0, 1);
  G_GATE(0);
  __builtin_amdgcn_s_barrier();

#pragma unroll 1
  for (int kt = 0; kt < 31; ++kt) {
    const int bufel = (kt & 1) * 16384;
    s16x8 b0[4], b1[4], a00[4], a01[4], a10[4], a11[4];
    G_LDB4(b0, bufel, 0);
    G_LDA4(a00, bufel, 0, 0);
    G_STAGE(kt + 1, 0);
    G_LDA4(a01, bufel, 0, 1);
    G_STAGE(kt + 1, 1);
    G_MMA2(0, a00, b0);          // ph0; a01/b1/a10 reads drain under MFMA
    G_LDB4(b1, bufel, 1);
    G_LDA4(a10, bufel, 1, 0);
    G_MMA2(1, a01, b0);          // ph1
    G_LDA4(a11, bufel, 1, 1);
    G_MMA2(0, a10, b1);          // ph2
    G_MMA2(1, a11, b1);          // ph3
    G_GATE(0);                   // tile kt+1 staged (8 loads this tile)
    __builtin_amdgcn_s_barrier();
  }
  {  // kt = 31 (buf 1): drain tile, no staging
    s16x8 b0[4], b1[4], a00[4], a01[4], a10[4], a11[4];
    G_LDB4(b0, 16384, 0);
    G_LDA4(a00, 16384, 0, 0);
    G_LDA4(a01, 16384, 0, 1);
    G_MMA2(0, a00, b0);
    G_LDB4(b1, 16384, 1);
    G_LDA4(a10, 16384, 1, 0);
    G_MMA2(1, a01, b0);
    G_LDA4(a11, 16384, 1, 1);
    G_MMA2(0, a10, b1);
    G_MMA2(1, a11, b1);
  }

  // epilogue: C[m][n], row = m0 + wm*128 + mh*64 + mt*16 + q*4 + r, col += l16
#pragma unroll
  for (int mh = 0; mh < 2; ++mh)
#pragma unroll
    for (int mt = 0; mt < 4; ++mt)
#pragma unroll
      for (int nt = 0; nt < 4; ++nt)
#pragma unroll
        for (int r = 0; r < 4; ++r) {
          long m = m0 + wm * 128 + mh * 64 + mt * 16 + q * 4 + r;
          long n = n0 + wn * 64 + nt * 16 + l16;
          C[m * 2048 + n] = f2bf(acc[mh * 4 + mt][nt][r]);
        }
}

// ---------------- K_rec: persistent LSTM scan (round-4 structure kept) -----
// 256 blocks (bt 0..15, g 0..15), 4 waves. Wave w owns k-chunks 4w..4w+3 for
// ALL 4 gate quadrants of this block's 32 gate cols. h fragments load from
// h_buf (L3) to registers per chunk; own chunk g served from LDS mirror.
// Cross-wave partials reduce through per-wave slabs [(w*4+quad)*32+col][row
// pad36]. w_hh fragments loaded ONCE via volatile asm global_load_dwordx4
// (not rematerializable -> VGPR-resident).
__global__ __launch_bounds__(256, 1) void k_rec(const unsigned short* __restrict__ gx,
                                                const unsigned short* __restrict__ whh_b,
                                                const float* __restrict__ b_ih,
                                                const float* __restrict__ b_hh,
                                                unsigned short* __restrict__ h_buf,
                                                float* __restrict__ out,
                                                unsigned int* __restrict__ bar) {
  __shared__ __align__(16) float slab[16 * 32 * 36];      // 73728 B
  __shared__ __align__(16) unsigned short hs_own[32 * 40];// own h slice mirror
  const int tid = threadIdx.x;
  const int w = tid >> 6, lane = tid & 63;
  const int q = lane >> 4, l16 = lane & 15;
  const int bt = blockIdx.x & 15, g = blockIdx.x >> 4;
  const int b0 = bt * 32;
  const int pj = tid & 31;              // pointwise: col within g-block
  const int pr0 = (tid >> 5) * 4;       // pointwise: rows pr0..pr0+3
  unsigned int* slots = &bar[bt * 16];
  const int ownw = ((g >> 2) == w);     // this wave's range contains chunk g
  const int ownc = g & 3;

  // w_hh fragments -> registers, once, via volatile asm loads
  s16x8 wreg[32];  // [(quad*2+nt)*4 + ci]
#pragma unroll
  for (int quad = 0; quad < 4; ++quad)
#pragma unroll
    for (int nt = 0; nt < 2; ++nt)
#pragma unroll
      for (int ci = 0; ci < 4; ++ci) {
        const unsigned short* wp =
            whh_b + (long)(quad * 512 + g * 32 + nt * 16 + l16) * 512 + (w * 4 + ci) * 32 + q * 8;
        asm volatile("global_load_dwordx4 %0, %1, off"
                     : "=v"(wreg[(quad * 2 + nt) * 4 + ci]) : "v"(wp) : "memory");
      }
  asm volatile("s_waitcnt vmcnt(0)" ::: "memory");
  __builtin_amdgcn_sched_barrier(0);

  float bias_[4];
#pragma unroll
  for (int qq = 0; qq < 4; ++qq) {
    int jj = qq * 512 + g * 32 + pj;
    bias_[qq] = b_ih[jj] + b_hh[jj];
  }
  float creg[4] = {0.f, 0.f, 0.f, 0.f};
  const f32x4 zz = {0.f, 0.f, 0.f, 0.f};

#define LD_CHUNK(slot, ci)                                                      \
  do {                                                                          \
    long o_ = hbase + (w * 4 + (ci)) * 8;                                       \
    L[slot][0] = ld_sys_u64(hb + o_);                                           \
    L[slot][1] = ld_sys_u64(hb + o_ + 1);                                       \
    L[slot][2] = ld_sys_u64(hb + o_ + 2048);                                    \
    L[slot][3] = ld_sys_u64(hb + o_ + 2049);                                    \
  } while (0)

  for (int t = 0; t < 48; ++t) {
    // gx prefetch (16 scalar u16; issued before any waiting)
    unsigned short gxr[4][4];
    const unsigned short* gp = gx + ((long)t * 512 + b0 + pr0) * 2048 + g * 32 + pj;
#pragma unroll
    for (int rr = 0; rr < 4; ++rr)
#pragma unroll
      for (int qq = 0; qq < 4; ++qq)
        gxr[qq][rr] = gp[rr * 2048 + qq * 512];

    if (t > 0) {
      // wait this wave's producer flags (lanes 0..3 poll; own chunk exempt)
      const int need = (lane < 4) && !(ownw && lane == ownc);
      const unsigned* fp = &slots[w * 4 + (lane & 3)];
      while (1) {
        unsigned v = need ? ld_sys_u32(fp) : 0xffffffffu;
        if (__all((int)(v >= (unsigned)t))) break;
      }
      // chunk pipeline: sys loads (L3) double-buffered, MFMA per chunk
      u64 L[2][4];
      const u64* hb = (const u64*)(h_buf + ((t - 1) & 1) * (512 * 512));
      const long hbase = (long)(b0 + l16) * 128 + q * 2;
      f32x4 acc[4][2][2];
#pragma unroll
      for (int a = 0; a < 4; ++a)
#pragma unroll
        for (int b = 0; b < 2; ++b)
#pragma unroll
          for (int c = 0; c < 2; ++c) acc[a][b][c] = zz;
      if (!(ownw && 0 == ownc)) LD_CHUNK(0, 0);
#pragma unroll
      for (int ci = 0; ci < 4; ++ci) {
        if (ci < 3 && !(ownw && (ci + 1) == ownc)) LD_CHUNK((ci + 1) & 1, ci + 1);
        s16x8 af0, af1;
        if (ownw && ci == ownc) {
          af0 = *(const s16x8*)&hs_own[l16 * 40 + q * 8];
          af1 = *(const s16x8*)&hs_own[(16 + l16) * 40 + q * 8];
        } else {
          union { u64 u[2]; s16x8 v; } c0, c1;
          c0.u[0] = L[ci & 1][0]; c0.u[1] = L[ci & 1][1];
          c1.u[0] = L[ci & 1][2]; c1.u[1] = L[ci & 1][3];
          af0 = c0.v; af1 = c1.v;
        }
#pragma unroll
        for (int quad = 0; quad < 4; ++quad)
#pragma unroll
          for (int nt = 0; nt < 2; ++nt) {
            acc[quad][nt][0] = __builtin_amdgcn_mfma_f32_16x16x32_bf16(
                af0, wreg[(quad * 2 + nt) * 4 + ci], acc[quad][nt][0], 0, 0, 0);
            acc[quad][nt][1] = __builtin_amdgcn_mfma_f32_16x16x32_bf16(
                af1, wreg[(quad * 2 + nt) * 4 + ci], acc[quad][nt][1], 0, 0, 0);
          }
      }
      // partials -> slab (f32x4 over rows, conflict-free)
#pragma unroll
      for (int quad = 0; quad < 4; ++quad)
#pragma unroll
        for (int nt = 0; nt < 2; ++nt)
#pragma unroll
          for (int mh = 0; mh < 2; ++mh)
            *(f32x4*)&slab[((w * 4 + quad) * 32 + nt * 16 + l16) * 36 + mh * 16 + q * 4] =
                acc[quad][nt][mh];
    }
    __syncthreads();

    // pointwise: thread owns (col g*32+pj, rows b0+pr0..+3)
    float hval[4];
    {
      f32x4 gs[4];
      if (t > 0) {
#pragma unroll
        for (int qq = 0; qq < 4; ++qq) {
          f32x4 s0 = *(const f32x4*)&slab[((0 * 4 + qq) * 32 + pj) * 36 + pr0];
          f32x4 s1 = *(const f32x4*)&slab[((1 * 4 + qq) * 32 + pj) * 36 + pr0];
          f32x4 s2 = *(const f32x4*)&slab[((2 * 4 + qq) * 32 + pj) * 36 + pr0];
          f32x4 s3 = *(const f32x4*)&slab[((3 * 4 + qq) * 32 + pj) * 36 + pr0];
          gs[qq] = (s0 + s1) + (s2 + s3);
        }
      } else {
#pragma unroll
        for (int qq = 0; qq < 4; ++qq) gs[qq] = zz;
      }
#pragma unroll
      for (int rr = 0; rr < 4; ++rr) {
        float g0 = gs[0][rr] + bias_[0] + bf2f(gxr[0][rr]);
        float g1 = gs[1][rr] + bias_[1] + bf2f(gxr[1][rr]);
        float g2 = gs[2][rr] + bias_[2] + bf2f(gxr[2][rr]);
        float g3 = gs[3][rr] + bias_[3] + bf2f(gxr[3][rr]);
        float is = fsig(g0);
        float fs = fsig(g1);
        float gt = ftanh(g2);
        float os = fsig(g3);
        creg[rr] = fs * creg[rr] + is * gt;
        hval[rr] = os * ftanh(creg[rr]);
      }
    }
    // publish h: LDS mirror (own chunk) + system-scope stores (L3, others)
#pragma unroll
    for (int rr = 0; rr < 4; ++rr) {
      unsigned short hb16 = f2bf(hval[rr]);
      hs_own[(pr0 + rr) * 40 + pj] = hb16;
      st_sys_u16(&h_buf[(t & 1) * (512 * 512) + (b0 + pr0 + rr) * 512 + g * 32 + pj], hb16);
    }
    __syncthreads();   // drains vmcnt(0): h stores at L3 before flag
    if (t < 47 && tid == 0)
      st_sys_u32(&slots[g], (unsigned)(t + 1));
    // out stores after the flag publish (drain overlaps next step's poll)
#pragma unroll
    for (int rr = 0; rr < 4; ++rr)
      __builtin_nontemporal_store(
          hval[rr], &out[(long)(b0 + pr0 + rr) * (T_ * H_) + (long)t * H_ + g * 32 + pj]);
  }
#undef LD_CHUNK
}

extern "C" void kernel_launch(void* const* d_in, const int* in_sizes, int n_in,
                              void* d_out, int out_size, void* d_ws, size_t ws_size,
                              hipStream_t stream) {
  const float* input  = (const float*)d_in[0];
  const float* attn_w = (const float*)d_in[1];
  const float* attn_b = (const float*)d_in[2];
  const float* w_ih   = (const float*)d_in[3];
  const float* w_hh   = (const float*)d_in[4];
  const float* b_ih   = (const float*)d_in[5];
  const float* b_hh   = (const float*)d_in[6];
  float* out = (float*)d_out;

  char* ws = (char*)d_ws;
  unsigned int* bar     = (unsigned int*)ws;                   // [0, 1024)
  float* a_ws           = (float*)(ws + 1024);                 // 512*128*4    = 262144
  unsigned short* h_buf = (unsigned short*)(ws + 263168);      // 2*512*512*2  = 1048576
  unsigned short* whh_b = (unsigned short*)(ws + 1311744);     // 2048*512*2   = 2097152
  unsigned short* wih_b = (unsigned short*)(ws + 3408896);     // 2048*2048*2  = 8388608
  unsigned short* x_hat = (unsigned short*)(ws + 11797504);    // 24576*2048*2 = 100663296
  unsigned short* gxws  = (unsigned short*)(ws + 112460800);   // 24576*2048*2 = 100663296

  (void)hipMemsetAsync(d_ws, 0, 1024, stream);
  hipLaunchKernelGGL(k_prep, dim3(5120), dim3(256), 0, stream, w_ih, w_hh, wih_b, whh_b);
  hipLaunchKernelGGL(k_ex, dim3(512), dim3(256), 0, stream, input, attn_w, attn_b, a_ws);
  hipLaunchKernelGGL(k_xhat, dim3(24576), dim3(256), 0, stream, input, a_ws, x_hat);
  hipLaunchKernelGGL(k_gemm, dim3(768), dim3(512), 0, stream, x_hat, wih_b, gxws);
  hipLaunchKernelGGL(k_rec, dim3(256), dim3(256), 0, stream, gxws, whh_b, b_ih, b_hh, h_buf, out, bar);
}